// Round 5
// baseline (352.949 us; speedup 1.0000x reference)
//
#include <hip/hip_runtime.h>
#include <math.h>

#define L_SEQ 2048
#define B_SZ 16
#define DIN 64
#define H_SZ 512
#define N_ST 64
#define N_LAYERS 4
#define Q_CHUNK 64
#define N_CHUNKS (L_SEQ / Q_CHUNK)   // 32
#define GSZ 4                         // chunks per pipeline group
#define N_GROUPS (N_CHUNKS / GSZ)     // 8
#define NTHR 768                      // 12 waves: 4 scan + 4 out + 4 aux

// XOR bank swizzle (m214 pattern): permute 16-B slots within a 128-B window by row.
// Applied identically at EVERY U_all / S_buf access site.
#define USWZ(b, colf16) ((((colf16) * 2)) ^ (((b) & 7) << 4))

typedef _Float16 f16;
typedef _Float16 f16x8 __attribute__((ext_vector_type(8)));
typedef _Float16 f16x4 __attribute__((ext_vector_type(4)));
typedef float    f32x4 __attribute__((ext_vector_type(4)));

struct cx { float r, i; };
__device__ __forceinline__ cx cmul(cx a, cx b) {
    return { a.r * b.r - a.i * b.i, a.r * b.i + a.i * b.r };
}

// LDS-only barrier (global loads/stores may stay in flight across it)
__device__ __forceinline__ void barrier_lgkm() {
    asm volatile("s_waitcnt lgkmcnt(0)\n\ts_barrier" ::: "memory");
}

// ---------- encoder (MFMA): out[h][b][l] = f16( sum_k x[l][b][k] W[k][h] + bias[h] ) ----------
__global__ __launch_bounds__(256, 4)
void encoder_mfma_kernel(const float* __restrict__ x, const float* __restrict__ W,
                         const float* __restrict__ bias, f16* __restrict__ out)
{
    __shared__ f16   x_sh[64][72];    // [l][k]
    __shared__ f16   w_t[64][72];     // [h][k]
    __shared__ float out_sh[64][68];
    __shared__ float b_sh[64];
    const int tid = threadIdx.x;
    const int bid = blockIdx.x;
    const int bb  = bid & 15;
    const int lt  = (bid >> 4) & 31;
    const int ht  = bid >> 9;
    const int l0 = lt * 64, h0 = ht * 64;

#pragma unroll
    for (int i = 0; i < 16; ++i) {
        int idx = tid + i * 256;
        int r = idx >> 6, c = idx & 63;
        x_sh[r][c] = (f16)x[((size_t)(l0 + r) * B_SZ + bb) * DIN + c];  // r=l, c=k
        w_t[c][r]  = (f16)W[(size_t)r * H_SZ + h0 + c];                 // r=k, c=h
    }
    if (tid < 64) b_sh[tid] = bias[h0 + tid];
    __syncthreads();

    const int wave = tid >> 6;
    const int lane = tid & 63;
    const int frow = lane & 15;
    const int fk   = (lane >> 4) * 8;
    const int m0   = wave * 16;            // h strip per wave

    f16x8 a0 = *(const f16x8*)&w_t[m0 + frow][fk];
    f16x8 a1 = *(const f16x8*)&w_t[m0 + frow][fk + 32];
    float bv[4];
#pragma unroll
    for (int j = 0; j < 4; ++j) bv[j] = b_sh[m0 + (lane >> 4) * 4 + j];

#pragma unroll
    for (int nt = 0; nt < 4; ++nt) {       // l tiles
        f16x8 b0 = *(const f16x8*)&x_sh[nt * 16 + frow][fk];
        f16x8 b1 = *(const f16x8*)&x_sh[nt * 16 + frow][fk + 32];
        f32x4 acc = {0.f, 0.f, 0.f, 0.f};
        acc = __builtin_amdgcn_mfma_f32_16x16x32_f16(a0, b0, acc, 0, 0, 0);
        acc = __builtin_amdgcn_mfma_f32_16x16x32_f16(a1, b1, acc, 0, 0, 0);
#pragma unroll
        for (int j = 0; j < 4; ++j)
            out_sh[m0 + (lane >> 4) * 4 + j][nt * 16 + frow] = acc[j] + bv[j];
    }
    __syncthreads();

#pragma unroll
    for (int i = 0; i < 4; ++i) {
        int row = (tid >> 4) + i * 16;     // h row
        int c4  = (tid & 15) * 4;          // l col
        f32x4 v = *(const f32x4*)&out_sh[row][c4];
        f16x4 o;
#pragma unroll
        for (int k = 0; k < 4; ++k) o[k] = (f16)v[k];
        *(f16x4*)&out[((size_t)(h0 + row) * B_SZ + bb) * L_SEQ + l0 + c4] = o;
    }
}

// ---------- fused 4-layer S4D: one block per h, sequence LDS-resident ----------
// 12 waves. Roles in the group-pipelined main loop (1 barrier per group-iter):
//   waves 0-3 ("scan"): wave w owns n in [16w,16w+16): publish S_pre -> S_buf;
//                       Z = E.U (4 MFMA); register scan, 4 complex pairs/lane.
//   waves 4-7 ("out"):  wave 4+jc owns chunk jc of the group, FULL 64 rows:
//                       y = T.U + G.S + D*u (24 MFMA), group lag 1;
//                       in-place writeback to U_all at lag 2 (layers 0-2),
//                       global f16 store at layer 3.
//   waves 8-11 ("aux"): during layer l (l<3) build layer l+1 tables into
//                       A_lds/G_lds (dead after layer-l fragment preload):
//                       g==1 power chains (E,G,w,dBv); g==2 K-dot; g==3 Toeplitz.
//                       Ordering provided by the existing per-iter barriers.
// U_all and S_buf accesses are XOR-swizzled (USWZ) against bank conflicts.
__global__ __launch_bounds__(NTHR, 3)
void s4d_fused_kernel(f16* __restrict__ u_io,          // [H][B][L] f16: encoder out; final y in place
                      const float* __restrict__ log_dt, const float* __restrict__ log_A_re,
                      const float* __restrict__ A_im, const float* __restrict__ C_re,
                      const float* __restrict__ C_im, const float* __restrict__ Dskip,
                      float* __restrict__ st_re, float* __restrict__ st_im)
{
    __shared__ f16   A_lds[192][72];         // 0-63: Toeplitz(K); 64-127: E_re[n][m]; 128-191: E_im[n][m]
    __shared__ f16   G_lds[65][136];         // G_ext[j][n2], j=0..64
    __shared__ f16   U_all[16][2048];        // per-h sequence, f16, swizzled, in place across layers
    __shared__ f16   S_buf[2][GSZ][16][128]; // S_pre per chunk of group [b][n2], swizzled
    __shared__ float dBv_sh[128];            // (dBr,dBi) interleaved per n
    __shared__ float K_sh[64];
    __shared__ float w_sh[64][2];            // dA^64 per n
    // total: 27648+17680+65536+32768+512+256+512 = 144912 B -> 1 block/CU

    const int tid  = threadIdx.x;
    const int wave = tid >> 6;
    const int lane = tid & 63;
    const int h    = blockIdx.x;
    const int frow = lane & 15;
    const int fq   = lane >> 4;
    const int fk   = fq * 8;

    // ---- stage the whole layer-0 input sequence into LDS (swizzled) ----
    {
        const f16* ub = u_io + (size_t)h * B_SZ * L_SEQ;
        for (int u0 = tid; u0 < 16 * 256; u0 += NTHR) {
            int b = u0 >> 8, c8 = (u0 & 255) * 8;
            f16x8 v = *(const f16x8*)&ub[(size_t)b * L_SEQ + c8];
            *(f16x8*)((char*)U_all[b] + USWZ(b, c8)) = v;
        }
    }
    f16* yb = u_io + (size_t)h * B_SZ * L_SEQ;   // final-layer f16 output (same h slot, safe)

    for (int layer = 0; layer < N_LAYERS; ++layer) {
        const int ph = layer * H_SZ + h;
        const int pn = ph * N_ST + lane;

        if (layer == 0) {
            // ---- layer-0 table build: 12 waves = 4 roles x 3 power segments ----
            {
                float dt   = expf(log_dt[ph]);
                float Are  = -expf(log_A_re[pn]);
                float Aim  = A_im[pn];
                float mg   = expf(dt * Are);
                float phs  = dt * Aim;
                cx dA1 = { mg * cosf(phs), mg * sinf(phs) };
                float invd = 1.0f / (Are * Are + Aim * Aim);
                float nr   = dA1.r - 1.0f;
                float dBr  = (nr * Are + dA1.i * Aim) * invd;
                float dBi  = (dA1.i * Are - nr * Aim) * invd;
                float Cr   = C_re[pn];
                float Ci   = C_im[pn];
                if (wave == 0) { dBv_sh[2 * lane] = dBr; dBv_sh[2 * lane + 1] = dBi; }

                const int role = wave & 3;     // 0:E_re 1:E_im 2:G_even 3:G_odd(+w)
                const int seg  = wave >> 2;    // 0,1,2
                cx dA2  = cmul(dA1, dA1);
                cx dA4  = cmul(dA2, dA2);
                cx dA8  = cmul(dA4, dA4);
                cx dA16 = cmul(dA8, dA8);
                cx P = { 1.f, 0.f };
                int j0 = 0, jend = 21;
                if (seg >= 1) { P = cmul(cmul(dA16, dA4), dA1); j0 = 21; jend = 42; }   // dA^21
                if (seg == 2) { P = cmul(P, P); j0 = 42; jend = (role >= 2) ? 65 : 64; } // dA^42
                for (int j = j0; j < jend; ++j) {
                    if (role == 0)      A_lds[64  + lane][63 - j] = (f16)(P.r * dBr - P.i * dBi);
                    else if (role == 1) A_lds[128 + lane][63 - j] = (f16)(P.r * dBi + P.i * dBr);
                    else if (role == 2) G_lds[j][2 * lane]     = (f16)( 2.f * (Cr * P.r - Ci * P.i));
                    else {
                        G_lds[j][2 * lane + 1] = (f16)(-2.f * (Cr * P.i + Ci * P.r));
                        if (j == 64) { w_sh[lane][0] = P.r; w_sh[lane][1] = P.i; }
                    }
                    P = cmul(P, dA1);
                }
            }
            barrier_lgkm();
            // K[d] = G_ext[d] . dBv  (8 lanes per d)
            if (tid < 512) {
                const int t  = tid >> 3;
                const int l8 = tid & 7;
                f16x8 g0 = *(const f16x8*)&G_lds[t][l8 * 16];
                f16x8 g1 = *(const f16x8*)&G_lds[t][l8 * 16 + 8];
                f32x4 d0 = *(const f32x4*)&dBv_sh[l8 * 16];
                f32x4 d1 = *(const f32x4*)&dBv_sh[l8 * 16 + 4];
                f32x4 d2 = *(const f32x4*)&dBv_sh[l8 * 16 + 8];
                f32x4 d3 = *(const f32x4*)&dBv_sh[l8 * 16 + 12];
                float acc = 0.f;
#pragma unroll
                for (int k = 0; k < 4; ++k) {
                    acc += (float)g0[k]     * d0[k];
                    acc += (float)g0[k + 4] * d1[k];
                    acc += (float)g1[k]     * d2[k];
                    acc += (float)g1[k + 4] * d3[k];
                }
                acc += __shfl_xor(acc, 1);
                acc += __shfl_xor(acc, 2);
                acc += __shfl_xor(acc, 4);
                if (l8 == 0) K_sh[t] = acc;
            }
            barrier_lgkm();
            for (int e = tid; e < 64 * 64; e += NTHR) {   // Toeplitz expansion
                int i = e >> 6, jc = e & 63;
                A_lds[i][jc] = (jc <= i) ? (f16)K_sh[i - jc] : (f16)0.f;
            }
            barrier_lgkm();
        }

        // ---- per-role chunk-invariant fragments / constants ----
        const float Dv = Dskip[ph];
        f16x8 aRe0, aRe1, aIm0, aIm1;            // scan
        f16x8 aT[4][2], aG[4][4];                // out (full 64 rows)
        float wr4[4], wi4[4];
        float s_r[4] = {0.f,0.f,0.f,0.f}, s_i[4] = {0.f,0.f,0.f,0.f};
        if (wave < 4) {
            const int m0 = 16 * wave;
            aRe0 = *(const f16x8*)&A_lds[64  + m0 + frow][fk];
            aRe1 = *(const f16x8*)&A_lds[64  + m0 + frow][fk + 32];
            aIm0 = *(const f16x8*)&A_lds[128 + m0 + frow][fk];
            aIm1 = *(const f16x8*)&A_lds[128 + m0 + frow][fk + 32];
#pragma unroll
            for (int p = 0; p < 4; ++p) {
                int n = m0 + fq * 4 + p;
                wr4[p] = w_sh[n][0]; wi4[p] = w_sh[n][1];
            }
        } else if (wave < 8) {
#pragma unroll
            for (int mt = 0; mt < 4; ++mt) {
                aT[mt][0] = *(const f16x8*)&A_lds[16 * mt + frow][fk];
                aT[mt][1] = *(const f16x8*)&A_lds[16 * mt + frow][fk + 32];
#pragma unroll
                for (int ks = 0; ks < 4; ++ks)
                    aG[mt][ks] = *(const f16x8*)&G_lds[1 + 16 * mt + frow][fk + 32 * ks];
            }
        }
        f16x4 yh[4];   // out: held y (layers 0-2), set at g>=1 before first use at g>=2

        // ---- main pipelined group loop: ONE barrier per group-iteration ----
        for (int g = 0; g <= N_GROUPS + 1; ++g) {
            if (wave < 4) {                      // ---- scan ----
                if (g < N_GROUPS) {
                    const int gb = g & 1;
#pragma unroll
                    for (int j = 0; j < GSZ; ++j) {
                        f16x8 sf;
                        sf[0] = (f16)s_r[0]; sf[1] = (f16)s_i[0];
                        sf[2] = (f16)s_r[1]; sf[3] = (f16)s_i[1];
                        sf[4] = (f16)s_r[2]; sf[5] = (f16)s_i[2];
                        sf[6] = (f16)s_r[3]; sf[7] = (f16)s_i[3];
                        *(f16x8*)((char*)S_buf[gb][j][frow] + USWZ(frow, 32 * wave + fk)) = sf;
                        const int co = (g * GSZ + j) * 64;
                        f16x8 b0 = *(const f16x8*)((const char*)U_all[frow] + USWZ(frow, co + fk));
                        f16x8 b1 = *(const f16x8*)((const char*)U_all[frow] + USWZ(frow, co + fk + 32));
                        f32x4 aR = {0.f,0.f,0.f,0.f}, aI = {0.f,0.f,0.f,0.f};
                        aR = __builtin_amdgcn_mfma_f32_16x16x32_f16(aRe0, b0, aR, 0, 0, 0);
                        aR = __builtin_amdgcn_mfma_f32_16x16x32_f16(aRe1, b1, aR, 0, 0, 0);
                        aI = __builtin_amdgcn_mfma_f32_16x16x32_f16(aIm0, b0, aI, 0, 0, 0);
                        aI = __builtin_amdgcn_mfma_f32_16x16x32_f16(aIm1, b1, aI, 0, 0, 0);
#pragma unroll
                        for (int p = 0; p < 4; ++p) {
                            float nr2 = wr4[p] * s_r[p] - wi4[p] * s_i[p] + aR[p];
                            float ni2 = wi4[p] * s_r[p] + wr4[p] * s_i[p] + aI[p];
                            s_r[p] = nr2; s_i[p] = ni2;
                        }
                    }
                }
            } else if (wave < 8) {               // ---- out: full 64 rows, one chunk ----
                const int jc = wave - 4;
                if (layer < N_LAYERS - 1 && g >= 2) {    // writeback group g-2
                    const int co2 = ((g - 2) * GSZ + jc) * 64;
#pragma unroll
                    for (int mt = 0; mt < 4; ++mt)
                        *(f16x4*)((char*)U_all[frow] + USWZ(frow, co2 + 16 * mt + fq * 4)) = yh[mt];
                }
                if (g >= 1 && g <= N_GROUPS) {           // compute group g-1
                    const int gp = g - 1, pb = gp & 1;
                    const int co = (gp * GSZ + jc) * 64;
                    f16x8 b0 = *(const f16x8*)((const char*)U_all[frow] + USWZ(frow, co + fk));
                    f16x8 b1 = *(const f16x8*)((const char*)U_all[frow] + USWZ(frow, co + fk + 32));
                    f16x8 sv0 = *(const f16x8*)((const char*)S_buf[pb][jc][frow] + USWZ(frow, fk));
                    f16x8 sv1 = *(const f16x8*)((const char*)S_buf[pb][jc][frow] + USWZ(frow, fk + 32));
                    f16x8 sv2 = *(const f16x8*)((const char*)S_buf[pb][jc][frow] + USWZ(frow, fk + 64));
                    f16x8 sv3 = *(const f16x8*)((const char*)S_buf[pb][jc][frow] + USWZ(frow, fk + 96));
#pragma unroll
                    for (int mt = 0; mt < 4; ++mt) {
                        f32x4 acc = {0.f,0.f,0.f,0.f};
                        acc = __builtin_amdgcn_mfma_f32_16x16x32_f16(aT[mt][0], b0, acc, 0, 0, 0);
                        acc = __builtin_amdgcn_mfma_f32_16x16x32_f16(aT[mt][1], b1, acc, 0, 0, 0);
                        acc = __builtin_amdgcn_mfma_f32_16x16x32_f16(aG[mt][0], sv0, acc, 0, 0, 0);
                        acc = __builtin_amdgcn_mfma_f32_16x16x32_f16(aG[mt][1], sv1, acc, 0, 0, 0);
                        acc = __builtin_amdgcn_mfma_f32_16x16x32_f16(aG[mt][2], sv2, acc, 0, 0, 0);
                        acc = __builtin_amdgcn_mfma_f32_16x16x32_f16(aG[mt][3], sv3, acc, 0, 0, 0);
                        const int t0 = 16 * mt + fq * 4;
                        f16x4 uf = *(const f16x4*)((const char*)U_all[frow] + USWZ(frow, co + t0));
                        f16x4 o;
#pragma unroll
                        for (int k = 0; k < 4; ++k) o[k] = (f16)(acc[k] + Dv * (float)uf[k]);
                        if (layer == N_LAYERS - 1)
                            *(f16x4*)&yb[(size_t)frow * L_SEQ + co + t0] = o;
                        else
                            yh[mt] = o;
                    }
                }
            } else {                             // ---- aux: build layer+1 tables ----
                if (layer < N_LAYERS - 1) {
                    if (g == 1) {
                        const int ph2 = (layer + 1) * H_SZ + h;
                        const int pn2 = ph2 * N_ST + lane;
                        float dt   = expf(log_dt[ph2]);
                        float Are  = -expf(log_A_re[pn2]);
                        float Aim  = A_im[pn2];
                        float mg   = expf(dt * Are);
                        float phs  = dt * Aim;
                        cx dA1 = { mg * cosf(phs), mg * sinf(phs) };
                        float invd = 1.0f / (Are * Are + Aim * Aim);
                        float nr   = dA1.r - 1.0f;
                        float dBr  = (nr * Are + dA1.i * Aim) * invd;
                        float dBi  = (dA1.i * Are - nr * Aim) * invd;
                        float Cr   = C_re[pn2];
                        float Ci   = C_im[pn2];
                        if (wave == 8) { dBv_sh[2 * lane] = dBr; dBv_sh[2 * lane + 1] = dBi; }
                        cx dA2  = cmul(dA1, dA1);
                        cx dA4  = cmul(dA2, dA2);
                        cx dA8  = cmul(dA4, dA4);
                        cx dA16 = cmul(dA8, dA8);
                        cx dA32 = cmul(dA16, dA16);
                        if (wave == 8 || wave == 9) {            // E chains
                            cx P = { 1.f, 0.f };
                            int j0 = 0, jend = 32;
                            if (wave == 9) { P = dA32; j0 = 32; jend = 64; }
                            for (int j = j0; j < jend; ++j) {
                                A_lds[64  + lane][63 - j] = (f16)(P.r * dBr - P.i * dBi);
                                A_lds[128 + lane][63 - j] = (f16)(P.r * dBi + P.i * dBr);
                                P = cmul(P, dA1);
                            }
                        } else {                                 // G chains (+w)
                            cx P = { 1.f, 0.f };
                            int j0 = 0, jend = 33;
                            if (wave == 11) { P = cmul(dA32, dA1); j0 = 33; jend = 65; }
                            for (int j = j0; j < jend; ++j) {
                                G_lds[j][2 * lane]     = (f16)( 2.f * (Cr * P.r - Ci * P.i));
                                G_lds[j][2 * lane + 1] = (f16)(-2.f * (Cr * P.i + Ci * P.r));
                                if (j == 64) { w_sh[lane][0] = P.r; w_sh[lane][1] = P.i; }
                                P = cmul(P, dA1);
                            }
                        }
                    } else if (g == 2) {                         // K-dot (256 aux threads)
                        const int idx = tid - 512;
                        const int t   = idx >> 2;
                        const int l4  = idx & 3;
                        const int base = l4 * 32;
                        f16x8 g0 = *(const f16x8*)&G_lds[t][base];
                        f16x8 g1 = *(const f16x8*)&G_lds[t][base + 8];
                        f16x8 g2 = *(const f16x8*)&G_lds[t][base + 16];
                        f16x8 g3 = *(const f16x8*)&G_lds[t][base + 24];
                        float acc = 0.f;
#pragma unroll
                        for (int k = 0; k < 8; ++k) {
                            acc += (float)g0[k] * dBv_sh[base + k];
                            acc += (float)g1[k] * dBv_sh[base + 8 + k];
                            acc += (float)g2[k] * dBv_sh[base + 16 + k];
                            acc += (float)g3[k] * dBv_sh[base + 24 + k];
                        }
                        acc += __shfl_xor(acc, 1);
                        acc += __shfl_xor(acc, 2);
                        if (l4 == 0) K_sh[t] = acc;
                    } else if (g == 3) {                         // Toeplitz expansion
                        for (int e = tid - 512; e < 64 * 64; e += 256) {
                            int i = e >> 6, jc2 = e & 63;
                            A_lds[i][jc2] = (jc2 <= i) ? (f16)K_sh[i - jc2] : (f16)0.f;
                        }
                    }
                }
            }
            barrier_lgkm();
        }

        // ---- final states from scan registers ----
        if (wave < 4) {
#pragma unroll
            for (int p = 0; p < 4; ++p) {
                int n = 16 * wave + 4 * fq + p;
                size_t base = (((size_t)layer * B_SZ + frow) * H_SZ + h) * N_ST + n;
                st_re[base] = s_r[p];
                st_im[base] = s_i[p];
            }
        }
        __syncthreads();   // tables / U_all safe for next layer's preload
    }
}

// ---------- [H][B][L] f16 -> [L][B][H] f32 transpose ----------
__global__ __launch_bounds__(256, 4)
void hbl_to_lbh_kernel(const f16* __restrict__ in, float* __restrict__ out)
{
    __shared__ float t_sh[64][65];
    const int tid = threadIdx.x, bid = blockIdx.x;
    const int bb = bid & 15, lt = (bid >> 4) & 31, ht = bid >> 9;
    const int l0 = lt * 64, h0 = ht * 64;
#pragma unroll
    for (int i = 0; i < 4; ++i) {
        int idx = tid + i * 256;
        int hh = idx >> 4, l4 = (idx & 15) * 4;
        f16x4 v = *(const f16x4*)&in[((size_t)(h0 + hh) * B_SZ + bb) * L_SEQ + l0 + l4];
#pragma unroll
        for (int k = 0; k < 4; ++k) t_sh[hh][l4 + k] = (float)v[k];
    }
    __syncthreads();
#pragma unroll
    for (int i = 0; i < 4; ++i) {
        int idx = tid + i * 256;
        int ll = idx >> 4, h4 = (idx & 15) * 4;
        float4 o = make_float4(t_sh[h4][ll], t_sh[h4 + 1][ll],
                               t_sh[h4 + 2][ll], t_sh[h4 + 3][ll]);
        *(float4*)&out[((size_t)(l0 + ll) * B_SZ + bb) * H_SZ + h0 + h4] = o;
    }
}

extern "C" void kernel_launch(void* const* d_in, const int* in_sizes, int n_in,
                              void* d_out, int out_size, void* d_ws, size_t ws_size,
                              hipStream_t stream)
{
    const float* x        = (const float*)d_in[0];
    const float* enc_W    = (const float*)d_in[1];
    const float* enc_b    = (const float*)d_in[2];
    const float* log_dt   = (const float*)d_in[3];
    const float* log_A_re = (const float*)d_in[4];
    const float* A_im     = (const float*)d_in[5];
    const float* C_re     = (const float*)d_in[6];
    const float* C_im     = (const float*)d_in[7];
    const float* Dskip    = (const float*)d_in[8];

    float* out_lbh = (float*)d_out;                                  // [L,B,H]
    float* st_re   = out_lbh + (size_t)L_SEQ * B_SZ * H_SZ;
    float* st_im   = st_re + (size_t)N_LAYERS * B_SZ * H_SZ * N_ST;
    f16*   B0      = (f16*)d_ws;     // [H][B][L] f16 activations (32 MB)

    encoder_mfma_kernel<<<4096, 256, 0, stream>>>(x, enc_W, enc_b, B0);

    s4d_fused_kernel<<<512, NTHR, 0, stream>>>(B0, log_dt, log_A_re, A_im,
                                               C_re, C_im, Dskip, st_re, st_im);

    hbl_to_lbh_kernel<<<4096, 256, 0, stream>>>(B0, out_lbh);        // final y -> [L,B,H]
}

// Round 7
// 242.878 us; speedup vs baseline: 1.4532x; 1.4532x over previous
//
#include <hip/hip_runtime.h>
#include <math.h>

#define L_SEQ 2048
#define B_SZ 16
#define DIN 64
#define H_SZ 512
#define N_ST 64
#define N_LAYERS 4
#define Q_CHUNK 64
#define N_CHUNKS (L_SEQ / Q_CHUNK)   // 32
#define GSZ 4                         // chunks per pipeline group
#define N_GROUPS (N_CHUNKS / GSZ)     // 8
#define UPAD 2056                     // U_all row stride in f16 (16B-aligned)
#define NTHR 768                      // 12 waves: 4 scan + 8 out

typedef _Float16 f16;
typedef _Float16 f16x8 __attribute__((ext_vector_type(8)));
typedef _Float16 f16x4 __attribute__((ext_vector_type(4)));
typedef float    f32x4 __attribute__((ext_vector_type(4)));

struct cx { float r, i; };
__device__ __forceinline__ cx cmul(cx a, cx b) {
    return { a.r * b.r - a.i * b.i, a.r * b.i + a.i * b.r };
}

// LDS-only barrier (global loads/stores may stay in flight across it)
__device__ __forceinline__ void barrier_lgkm() {
    asm volatile("s_waitcnt lgkmcnt(0)\n\ts_barrier" ::: "memory");
}

// ---------- encoder (MFMA): out[h][b][l] = f16( sum_k x[l][b][k] W[k][h] + bias[h] ) ----------
__global__ __launch_bounds__(256, 4)
void encoder_mfma_kernel(const float* __restrict__ x, const float* __restrict__ W,
                         const float* __restrict__ bias, f16* __restrict__ out)
{
    __shared__ f16   x_sh[64][72];    // [l][k]
    __shared__ f16   w_t[64][72];     // [h][k]
    __shared__ float out_sh[64][68];
    __shared__ float b_sh[64];
    const int tid = threadIdx.x;
    const int bid = blockIdx.x;
    const int bb  = bid & 15;
    const int lt  = (bid >> 4) & 31;
    const int ht  = bid >> 9;
    const int l0 = lt * 64, h0 = ht * 64;

#pragma unroll
    for (int i = 0; i < 16; ++i) {
        int idx = tid + i * 256;
        int r = idx >> 6, c = idx & 63;
        x_sh[r][c] = (f16)x[((size_t)(l0 + r) * B_SZ + bb) * DIN + c];  // r=l, c=k
        w_t[c][r]  = (f16)W[(size_t)r * H_SZ + h0 + c];                 // r=k, c=h
    }
    if (tid < 64) b_sh[tid] = bias[h0 + tid];
    __syncthreads();

    const int wave = tid >> 6;
    const int lane = tid & 63;
    const int frow = lane & 15;
    const int fk   = (lane >> 4) * 8;
    const int m0   = wave * 16;            // h strip per wave

    f16x8 a0 = *(const f16x8*)&w_t[m0 + frow][fk];
    f16x8 a1 = *(const f16x8*)&w_t[m0 + frow][fk + 32];
    float bv[4];
#pragma unroll
    for (int j = 0; j < 4; ++j) bv[j] = b_sh[m0 + (lane >> 4) * 4 + j];

#pragma unroll
    for (int nt = 0; nt < 4; ++nt) {       // l tiles
        f16x8 b0 = *(const f16x8*)&x_sh[nt * 16 + frow][fk];
        f16x8 b1 = *(const f16x8*)&x_sh[nt * 16 + frow][fk + 32];
        f32x4 acc = {0.f, 0.f, 0.f, 0.f};
        acc = __builtin_amdgcn_mfma_f32_16x16x32_f16(a0, b0, acc, 0, 0, 0);
        acc = __builtin_amdgcn_mfma_f32_16x16x32_f16(a1, b1, acc, 0, 0, 0);
#pragma unroll
        for (int j = 0; j < 4; ++j)
            out_sh[m0 + (lane >> 4) * 4 + j][nt * 16 + frow] = acc[j] + bv[j];
    }
    __syncthreads();

#pragma unroll
    for (int i = 0; i < 4; ++i) {
        int row = (tid >> 4) + i * 16;     // h row
        int c4  = (tid & 15) * 4;          // l col
        f32x4 v = *(const f32x4*)&out_sh[row][c4];
        f16x4 o;
#pragma unroll
        for (int k = 0; k < 4; ++k) o[k] = (f16)v[k];
        *(f16x4*)&out[((size_t)(h0 + row) * B_SZ + bb) * L_SEQ + l0 + c4] = o;
    }
}

// ---------- fused 4-layer S4D: one block per h, sequence LDS-resident ----------
// Round-4 proven structure + D folded into the Toeplitz diagonal:
//   waves 0-3 ("scan"): wave w owns n in [16w,16w+16): publish S_pre -> S_buf;
//                       Z_re/Z_im = E.U (4 MFMA); register scan, 4 pairs/lane.
//   waves 4-11 ("out"): wave = (chunk jc, m-half mh, 32 rows):
//                       y = (T + D.I).U + G.S  (12 MFMA), group lag 1;
//                       in-place writeback to U_all at lag 2 (layers 0-2),
//                       global f16 store at layer 3.
// All MFMA fragments are loaded UNCONDITIONALLY (no undef-lifetime registers).
__global__ __launch_bounds__(NTHR, 3)
void s4d_fused_kernel(f16* __restrict__ u_io,          // [H][B][L] f16: encoder out; final y in place
                      const float* __restrict__ log_dt, const float* __restrict__ log_A_re,
                      const float* __restrict__ A_im, const float* __restrict__ C_re,
                      const float* __restrict__ C_im, const float* __restrict__ Dskip,
                      float* __restrict__ st_re, float* __restrict__ st_im)
{
    __shared__ f16   A_lds[192][72];         // 0-63: Toeplitz(K)+D.I; 64-127: E_re[n][m]; 128-191: E_im[n][m]
    __shared__ f16   G_lds[65][136];         // G_ext[j][n2], j=0..64
    __shared__ f16   U_all[16][UPAD];        // whole per-h sequence, f16, in place across layers
    __shared__ f16   S_buf[2][GSZ][16][136]; // S_pre per chunk of group [b][n2]
    __shared__ float dBv_sh[128];            // (dBr,dBi) interleaved per n
    __shared__ float K_sh[64];
    __shared__ float w_sh[64][2];            // dA^64 per n
    // total: 27648+17680+65792+34816+512+256+512 = 147216 B -> 1 block/CU

    const int tid  = threadIdx.x;
    const int wave = tid >> 6;
    const int lane = tid & 63;
    const int h    = blockIdx.x;
    const int frow = lane & 15;
    const int fq   = lane >> 4;
    const int fk   = fq * 8;

    // ---- stage the whole layer-0 input sequence into LDS ----
    {
        const f16* ub = u_io + (size_t)h * B_SZ * L_SEQ;
        for (int u0 = tid; u0 < 16 * 256; u0 += NTHR) {
            int b = u0 >> 8, cidx = (u0 & 255) * 8;
            *(f16x8*)&U_all[b][cidx] = *(const f16x8*)&ub[(size_t)b * L_SEQ + cidx];
        }
    }
    f16* yb = u_io + (size_t)h * B_SZ * L_SEQ;   // final-layer f16 output (same h slot, safe)

    for (int layer = 0; layer < N_LAYERS; ++layer) {
        const int ph = layer * H_SZ + h;
        const int pn = ph * N_ST + lane;
        const float Dv = Dskip[ph];              // folded into Toeplitz diagonal below

        // ---- table build: 12 waves = 4 roles x 3 power segments ----
        {
            float dt   = expf(log_dt[ph]);
            float Are  = -expf(log_A_re[pn]);
            float Aim  = A_im[pn];
            float mg   = expf(dt * Are);
            float phs  = dt * Aim;
            cx dA1 = { mg * cosf(phs), mg * sinf(phs) };
            float invd = 1.0f / (Are * Are + Aim * Aim);
            float nr   = dA1.r - 1.0f;
            float dBr  = (nr * Are + dA1.i * Aim) * invd;
            float dBi  = (dA1.i * Are - nr * Aim) * invd;
            float Cr   = C_re[pn];
            float Ci   = C_im[pn];
            if (wave == 0) { dBv_sh[2 * lane] = dBr; dBv_sh[2 * lane + 1] = dBi; }

            const int role = wave & 3;     // 0:E_re 1:E_im 2:G_even 3:G_odd(+w)
            const int seg  = wave >> 2;    // 0,1,2
            cx dA2  = cmul(dA1, dA1);
            cx dA4  = cmul(dA2, dA2);
            cx dA8  = cmul(dA4, dA4);
            cx dA16 = cmul(dA8, dA8);
            cx P = { 1.f, 0.f };
            int j0 = 0, jend = 21;
            if (seg >= 1) { P = cmul(cmul(dA16, dA4), dA1); j0 = 21; jend = 42; }   // dA^21
            if (seg == 2) { P = cmul(P, P); j0 = 42; jend = (role >= 2) ? 65 : 64; } // dA^42
            for (int j = j0; j < jend; ++j) {
                if (role == 0)      A_lds[64  + lane][63 - j] = (f16)(P.r * dBr - P.i * dBi);
                else if (role == 1) A_lds[128 + lane][63 - j] = (f16)(P.r * dBi + P.i * dBr);
                else if (role == 2) G_lds[j][2 * lane]     = (f16)( 2.f * (Cr * P.r - Ci * P.i));
                else {
                    G_lds[j][2 * lane + 1] = (f16)(-2.f * (Cr * P.i + Ci * P.r));
                    if (j == 64) { w_sh[lane][0] = P.r; w_sh[lane][1] = P.i; }
                }
                P = cmul(P, dA1);
            }
        }
        barrier_lgkm();

        // ---- K[d] = G_ext[d] . dBv  (8 lanes per d) ----
        if (tid < 512) {
            const int t  = tid >> 3;
            const int l8 = tid & 7;
            f16x8 g0 = *(const f16x8*)&G_lds[t][l8 * 16];
            f16x8 g1 = *(const f16x8*)&G_lds[t][l8 * 16 + 8];
            f32x4 d0 = *(const f32x4*)&dBv_sh[l8 * 16];
            f32x4 d1 = *(const f32x4*)&dBv_sh[l8 * 16 + 4];
            f32x4 d2 = *(const f32x4*)&dBv_sh[l8 * 16 + 8];
            f32x4 d3 = *(const f32x4*)&dBv_sh[l8 * 16 + 12];
            float acc = 0.f;
#pragma unroll
            for (int k = 0; k < 4; ++k) {
                acc += (float)g0[k]     * d0[k];
                acc += (float)g0[k + 4] * d1[k];
                acc += (float)g1[k]     * d2[k];
                acc += (float)g1[k + 4] * d3[k];
            }
            acc += __shfl_xor(acc, 1);
            acc += __shfl_xor(acc, 2);
            acc += __shfl_xor(acc, 4);
            if (l8 == 0) K_sh[t] = acc;
        }
        barrier_lgkm();
        for (int e = tid; e < 64 * 64; e += NTHR) {   // Toeplitz expansion, D on diagonal
            int i = e >> 6, jc = e & 63;
            A_lds[i][jc] = (jc < i) ? (f16)K_sh[i - jc]
                         : (jc == i ? (f16)(K_sh[0] + Dv) : (f16)0.f);
        }
        barrier_lgkm();

        // ---- per-role chunk-invariant fragments / constants ----
        f16x8 aRe0, aRe1, aIm0, aIm1;            // scan
        f16x8 aT0[2], aT1[2], aG[2][4];          // out
        float wr4[4], wi4[4];
        float s_r[4] = {0.f,0.f,0.f,0.f}, s_i[4] = {0.f,0.f,0.f,0.f};
        if (wave < 4) {
            const int m0 = 16 * wave;
            aRe0 = *(const f16x8*)&A_lds[64  + m0 + frow][fk];
            aRe1 = *(const f16x8*)&A_lds[64  + m0 + frow][fk + 32];
            aIm0 = *(const f16x8*)&A_lds[128 + m0 + frow][fk];
            aIm1 = *(const f16x8*)&A_lds[128 + m0 + frow][fk + 32];
#pragma unroll
            for (int p = 0; p < 4; ++p) {
                int n = m0 + fq * 4 + p;
                wr4[p] = w_sh[n][0]; wi4[p] = w_sh[n][1];
            }
        } else {
            const int mh = (wave - 4) & 1;
#pragma unroll
            for (int mt = 0; mt < 2; ++mt) {
                const int r0 = 32 * mh + 16 * mt + frow;
                aT0[mt] = *(const f16x8*)&A_lds[r0][fk];
                aT1[mt] = *(const f16x8*)&A_lds[r0][fk + 32];
#pragma unroll
                for (int k4 = 0; k4 < 4; ++k4)
                    aG[mt][k4] = *(const f16x8*)&G_lds[1 + r0][fk + 32 * k4];
            }
        }
        f16x4 yh[2];   // out: held y (layers 0-2), set at g>=1 before first use at g>=2

        // ---- main pipelined group loop: ONE barrier per group-iteration ----
        for (int g = 0; g <= N_GROUPS + 1; ++g) {
            if (wave < 4) {                      // ---- scan ----
                if (g < N_GROUPS) {
                    const int gb = g & 1;
#pragma unroll
                    for (int j = 0; j < GSZ; ++j) {
                        f16x8 sf;
                        sf[0] = (f16)s_r[0]; sf[1] = (f16)s_i[0];
                        sf[2] = (f16)s_r[1]; sf[3] = (f16)s_i[1];
                        sf[4] = (f16)s_r[2]; sf[5] = (f16)s_i[2];
                        sf[6] = (f16)s_r[3]; sf[7] = (f16)s_i[3];
                        *(f16x8*)&S_buf[gb][j][frow][32 * wave + fk] = sf;
                        const int co = (g * GSZ + j) * 64;
                        f16x8 b0 = *(const f16x8*)&U_all[frow][co + fk];
                        f16x8 b1 = *(const f16x8*)&U_all[frow][co + fk + 32];
                        f32x4 aR = {0.f,0.f,0.f,0.f}, aI = {0.f,0.f,0.f,0.f};
                        aR = __builtin_amdgcn_mfma_f32_16x16x32_f16(aRe0, b0, aR, 0, 0, 0);
                        aR = __builtin_amdgcn_mfma_f32_16x16x32_f16(aRe1, b1, aR, 0, 0, 0);
                        aI = __builtin_amdgcn_mfma_f32_16x16x32_f16(aIm0, b0, aI, 0, 0, 0);
                        aI = __builtin_amdgcn_mfma_f32_16x16x32_f16(aIm1, b1, aI, 0, 0, 0);
#pragma unroll
                        for (int p = 0; p < 4; ++p) {
                            float nr2 = wr4[p] * s_r[p] - wi4[p] * s_i[p] + aR[p];
                            float ni2 = wi4[p] * s_r[p] + wr4[p] * s_i[p] + aI[p];
                            s_r[p] = nr2; s_i[p] = ni2;
                        }
                    }
                }
            } else {                             // ---- out: (chunk jc, m-half mh) ----
                const int ow = wave - 4, jc = ow >> 1, mh = ow & 1;
                if (layer < N_LAYERS - 1 && g >= 2) {    // writeback group g-2
                    const int co2 = ((g - 2) * GSZ + jc) * 64;
                    *(f16x4*)&U_all[frow][co2 + 32 * mh + fq * 4]      = yh[0];
                    *(f16x4*)&U_all[frow][co2 + 32 * mh + 16 + fq * 4] = yh[1];
                }
                if (g >= 1 && g <= N_GROUPS) {           // compute group g-1
                    const int gp = g - 1, pb = gp & 1;
                    const int co = (gp * GSZ + jc) * 64;
                    f16x8 b0 = *(const f16x8*)&U_all[frow][co + fk];
                    f16x8 b1 = *(const f16x8*)&U_all[frow][co + fk + 32];
                    f16x8 sv0 = *(const f16x8*)&S_buf[pb][jc][frow][fk];
                    f16x8 sv1 = *(const f16x8*)&S_buf[pb][jc][frow][fk + 32];
                    f16x8 sv2 = *(const f16x8*)&S_buf[pb][jc][frow][fk + 64];
                    f16x8 sv3 = *(const f16x8*)&S_buf[pb][jc][frow][fk + 96];
#pragma unroll
                    for (int mt = 0; mt < 2; ++mt) {
                        f32x4 acc = {0.f,0.f,0.f,0.f};
                        acc = __builtin_amdgcn_mfma_f32_16x16x32_f16(aT0[mt], b0, acc, 0, 0, 0);
                        acc = __builtin_amdgcn_mfma_f32_16x16x32_f16(aT1[mt], b1, acc, 0, 0, 0);
                        acc = __builtin_amdgcn_mfma_f32_16x16x32_f16(aG[mt][0], sv0, acc, 0, 0, 0);
                        acc = __builtin_amdgcn_mfma_f32_16x16x32_f16(aG[mt][1], sv1, acc, 0, 0, 0);
                        acc = __builtin_amdgcn_mfma_f32_16x16x32_f16(aG[mt][2], sv2, acc, 0, 0, 0);
                        acc = __builtin_amdgcn_mfma_f32_16x16x32_f16(aG[mt][3], sv3, acc, 0, 0, 0);
                        const int t0 = 32 * mh + 16 * mt + fq * 4;
                        f16x4 o;
#pragma unroll
                        for (int k = 0; k < 4; ++k) o[k] = (f16)acc[k];
                        if (layer == N_LAYERS - 1)
                            *(f16x4*)&yb[(size_t)frow * L_SEQ + co + t0] = o;
                        else
                            yh[mt] = o;
                    }
                }
            }
            barrier_lgkm();
        }

        // ---- final states from scan registers ----
        if (wave < 4) {
#pragma unroll
            for (int p = 0; p < 4; ++p) {
                int n = 16 * wave + 4 * fq + p;
                size_t base = (((size_t)layer * B_SZ + frow) * H_SZ + h) * N_ST + n;
                st_re[base] = s_r[p];
                st_im[base] = s_i[p];
            }
        }
        __syncthreads();   // tables / U_all safe to overwrite for next layer
    }
}

// ---------- [H][B][L] f16 -> [L][B][H] f32 transpose ----------
__global__ __launch_bounds__(256, 4)
void hbl_to_lbh_kernel(const f16* __restrict__ in, float* __restrict__ out)
{
    __shared__ float t_sh[64][65];
    const int tid = threadIdx.x, bid = blockIdx.x;
    const int bb = bid & 15, lt = (bid >> 4) & 31, ht = bid >> 9;
    const int l0 = lt * 64, h0 = ht * 64;
#pragma unroll
    for (int i = 0; i < 4; ++i) {
        int idx = tid + i * 256;
        int hh = idx >> 4, l4 = (idx & 15) * 4;
        f16x4 v = *(const f16x4*)&in[((size_t)(h0 + hh) * B_SZ + bb) * L_SEQ + l0 + l4];
#pragma unroll
        for (int k = 0; k < 4; ++k) t_sh[hh][l4 + k] = (float)v[k];
    }
    __syncthreads();
#pragma unroll
    for (int i = 0; i < 4; ++i) {
        int idx = tid + i * 256;
        int ll = idx >> 4, h4 = (idx & 15) * 4;
        float4 o = make_float4(t_sh[h4][ll], t_sh[h4 + 1][ll],
                               t_sh[h4 + 2][ll], t_sh[h4 + 3][ll]);
        *(float4*)&out[((size_t)(l0 + ll) * B_SZ + bb) * H_SZ + h0 + h4] = o;
    }
}

extern "C" void kernel_launch(void* const* d_in, const int* in_sizes, int n_in,
                              void* d_out, int out_size, void* d_ws, size_t ws_size,
                              hipStream_t stream)
{
    const float* x        = (const float*)d_in[0];
    const float* enc_W    = (const float*)d_in[1];
    const float* enc_b    = (const float*)d_in[2];
    const float* log_dt   = (const float*)d_in[3];
    const float* log_A_re = (const float*)d_in[4];
    const float* A_im     = (const float*)d_in[5];
    const float* C_re     = (const float*)d_in[6];
    const float* C_im     = (const float*)d_in[7];
    const float* Dskip    = (const float*)d_in[8];

    float* out_lbh = (float*)d_out;                                  // [L,B,H]
    float* st_re   = out_lbh + (size_t)L_SEQ * B_SZ * H_SZ;
    float* st_im   = st_re + (size_t)N_LAYERS * B_SZ * H_SZ * N_ST;
    f16*   B0      = (f16*)d_ws;     // [H][B][L] f16 activations (32 MB)

    encoder_mfma_kernel<<<4096, 256, 0, stream>>>(x, enc_W, enc_b, B0);

    s4d_fused_kernel<<<512, NTHR, 0, stream>>>(B0, log_dt, log_A_re, A_im,
                                               C_re, C_im, Dskip, st_re, st_im);

    hbl_to_lbh_kernel<<<4096, 256, 0, stream>>>(B0, out_lbh);        // final y -> [L,B,H]
}